// Round 14
// baseline (942.425 us; speedup 1.0000x reference)
//
#include <hip/hip_runtime.h>
#include <hip/hip_bf16.h>
#include <stdint.h>

// ---------------- problem constants ----------------
static constexpr int Hd   = 1024;     // H_DIM
static constexpr int BZn  = 256;      // batch
static constexpr int MTOT = 131072;   // 32 * 4096 keys
static constexpr int NU   = 7;        // units

typedef float  f32x4  __attribute__((ext_vector_type(4)));
typedef short  bf16x8 __attribute__((ext_vector_type(8)));
typedef short  bf16x4 __attribute__((ext_vector_type(4)));
typedef unsigned short u16;

__device__ __forceinline__ u16 f2bf(float f) {
    __hip_bfloat16 h = __float2bfloat16(f);   // RNE
    return *reinterpret_cast<u16*>(&h);
}

// Counted-wait barrier: waits LDS ops only; vmem loads stay in flight.
__device__ __forceinline__ void block_sync_lds() {
    asm volatile("s_waitcnt lgkmcnt(0)" ::: "memory");
    __builtin_amdgcn_s_barrier();
}

// ---------------- prep kernels ----------------

// Qrot[256][1024] = query @ R  (f32). 64 blocks x 256.
__global__ void k_qrot(const float* __restrict__ query, const float* __restrict__ R,
                       float* __restrict__ Qrot) {
    __shared__ float qt[4][Hd];
    const int t = threadIdx.x;
    const int r0 = blockIdx.x * 4;
    for (int r = 0; r < 4; ++r)
        *(float4*)(&qt[r][t * 4]) = *(const float4*)(query + (long long)(r0 + r) * Hd + t * 4);
    __syncthreads();
    float acc[4][4] = {};
    for (int k = 0; k < Hd; ++k) {
        float4 rv = *(const float4*)(R + (long long)k * Hd + t * 4);
#pragma unroll
        for (int r = 0; r < 4; ++r) {
            float qv = qt[r][k];
            acc[r][0] += qv * rv.x; acc[r][1] += qv * rv.y;
            acc[r][2] += qv * rv.z; acc[r][3] += qv * rv.w;
        }
    }
    for (int r = 0; r < 4; ++r) {
        float4 o; o.x = acc[r][0]; o.y = acc[r][1]; o.z = acc[r][2]; o.w = acc[r][3];
        *(float4*)(Qrot + (long long)(r0 + r) * Hd + t * 4) = o;
    }
}

// Rpack: B-fragment layout for mfma_f32_16x16x32_bf16.
// frag id = (c0/16)*32 + (k0/32); lane l holds B[k0+(l>>4)*8+j][c0+(l&15)], j=0..7.
// NOTE: identical per-lane data serves as the A-fragment of R^T (A[rcol][k]=R[k][rcol]).
__global__ void k_rpack(const float* __restrict__ R, u16* __restrict__ Rpack) {
    const int gt = blockIdx.x * 256 + threadIdx.x;
    const int frag = gt >> 6, lam = gt & 63;
    const int cblk = frag >> 5, kblk = frag & 31;
    const int c  = cblk * 16 + (lam & 15);
    const int k0 = kblk * 32 + (lam >> 4) * 8;
    union { bf16x8 v; u16 u[8]; } p;
#pragma unroll
    for (int j = 0; j < 8; ++j) p.u[j] = f2bf(R[(long long)(k0 + j) * Hd + c]);
    *(bf16x8*)(Rpack + (long long)frag * 512 + lam * 8) = p.v;
}

// Qpack: A-fragment layout. frag id = (c0/32)*16 + (q0/16);
// lane l holds A[q0+(l&15)][c0+(l>>4)*8+j].
__global__ void k_qpack(const float* __restrict__ Qrot, u16* __restrict__ Qpack) {
    const int gt = blockIdx.x * 256 + threadIdx.x;
    const int frag = gt >> 6, lam = gt & 63;
    const int cblk = frag >> 4, qblk = frag & 15;
    const int q  = qblk * 16 + (lam & 15);
    const int c0 = cblk * 32 + (lam >> 4) * 8;
    union { bf16x8 v; u16 u[8]; } p;
#pragma unroll
    for (int j = 0; j < 8; ++j) p.u[j] = f2bf(Qrot[(long long)q * Hd + c0 + j]);
    *(bf16x8*)(Qpack + (long long)frag * 512 + lam * 8) = p.v;
}

// ---------------- fused main: rotate 128keys x 256cols, then sims+argmax in-block ----
// LDS UNION (2 blocks/CU): abuf [0..20480) rotation-only; T [0..69632) + normP after.
static constexpr int LDS_ABUF0 = 0;
static constexpr int LDS_ABUF1 = 10240;
static constexpr int LDS_T     = 0;        // overlaps abuf (phase-separated)
static constexpr int LDS_NP    = 69632;    // 4 wc x 128 keys x f32 = 2048
static constexpr int LDS_TOT   = 73728;    // <= 80 KiB -> 2 blocks/CU

__global__ __launch_bounds__(512, 4)
void k_fused(const float* __restrict__ keys, const u16* __restrict__ Rp,
             const u16* __restrict__ Qp, unsigned long long* __restrict__ best) {
    extern __shared__ char smem[];
    char*  abuf0 = smem + LDS_ABUF0;
    char*  abuf1 = smem + LDS_ABUF1;
    char*  T     = smem + LDS_T;
    float* normP = (float*)(smem + LDS_NP);

    const int t   = threadIdx.x;
    const int lam = t & 63;
    const int w   = t >> 6;
    const int l15 = lam & 15;
    const int lg  = lam >> 4;
    const int wq  = w >> 2;            // rotation: key half
    const int wc  = w & 3;             // rotation: col quarter

    // T1: bijective XCD swizzle (8 XCDs, 4096 blocks -> 512 per XCD chunk)
    const int bid  = (blockIdx.x & 7) * 512 + (blockIdx.x >> 3);
    const int tkey = bid >> 2;
    const int cg   = bid & 3;          // 256-col group
    const int kb   = tkey * 128;

    // ---- A staging geometry: thread t stages row sr = t>>2, 8 floats at (t&3)*8 ----
    const int sr = t >> 2, sc = t & 3;
    const float* apt = keys + (long long)(kb + sr) * Hd + sc * 8;
    const int sdst = sr * 80 + sc * 16;

    // ---- R-frag stream base: cblk = cg*16 + wc*4 + n; fid = cblk*32 + s ----
    const char* bB = (const char*)Rp + (long long)((cg * 16 + wc * 4) * 32) * 1024 + lam * 16;

    // acc[mr][nk]: mr = rcol frag (rows of D), nk = key frag (cols of D).
    // Swapped-operand C/D: lane holds col=key (l15), rows = rcol lg*4+e (consecutive).
    f32x4 acc[4][4];
#pragma unroll
    for (int mr = 0; mr < 4; ++mr)
#pragma unroll
        for (int nk = 0; nk < 4; ++nk) acc[mr][nk] = (f32x4){0.f, 0.f, 0.f, 0.f};

    // prologue prefetch (stage 0)
    float4 ar0 = *(const float4*)(apt);
    float4 ar1 = *(const float4*)(apt + 4);
    bf16x8 nb[4];
#pragma unroll
    for (int n = 0; n < 4; ++n) nb[n] = *(const bf16x8*)(bB + (long long)(n * 32) * 1024);

#pragma unroll 2
    for (int s = 0; s < 32; ++s) {
        char* buf = (s & 1) ? abuf1 : abuf0;
        // convert + write staged A (one b128 per thread)
        union { bf16x8 v; u16 u[8]; } p;
        p.u[0] = f2bf(ar0.x); p.u[1] = f2bf(ar0.y); p.u[2] = f2bf(ar0.z); p.u[3] = f2bf(ar0.w);
        p.u[4] = f2bf(ar1.x); p.u[5] = f2bf(ar1.y); p.u[6] = f2bf(ar1.z); p.u[7] = f2bf(ar1.w);
        *(bf16x8*)(buf + sdst) = p.v;

        // prefetch next stage (clamped); loads stay in flight across the barrier
        const int sn = (s < 31) ? s + 1 : 31;
        ar0 = *(const float4*)(apt + sn * 32);
        ar1 = *(const float4*)(apt + sn * 32 + 4);
        bf16x8 cbv[4];
#pragma unroll
        for (int n = 0; n < 4; ++n) cbv[n] = nb[n];
#pragma unroll
        for (int n = 0; n < 4; ++n)
            nb[n] = *(const bf16x8*)(bB + (long long)(n * 32 + sn) * 1024);

        block_sync_lds();   // lgkmcnt(0) + raw barrier: NO vmcnt drain

#pragma unroll
        for (int m = 0; m < 4; ++m) {        // m = key frag (B-operand of swapped call)
            int row = wq * 64 + m * 16 + l15;
            bf16x8 a = *(const bf16x8*)(buf + row * 80 + lg * 16);
#pragma unroll
            for (int n = 0; n < 4; ++n)      // n = rcol frag (A-operand)
                acc[n][m] = __builtin_amdgcn_mfma_f32_16x16x32_bf16(cbv[n], a, acc[n][m], 0, 0, 0);
        }
    }
    block_sync_lds();   // rotation abuf reads done; T may overwrite abuf region

    // ---- norms: per-key partial over this wave's 64 rcols -> normP[wc][key] ----
    // lane-local sum over mr,e (16 rcols), then reduce across lg via 2 shfls.
#pragma unroll
    for (int nk = 0; nk < 4; ++nk) {
        float s = 0.f;
#pragma unroll
        for (int mr = 0; mr < 4; ++mr)
#pragma unroll
            for (int e = 0; e < 4; ++e) { float v = acc[mr][nk][e]; s = fmaf(v, v, s); }
        s += __shfl_xor(s, 16);
        s += __shfl_xor(s, 32);
        if (lam < 16) normP[wc * 128 + wq * 64 + nk * 16 + lam] = s;
    }

    // ---- bounce acc -> T subtiles (32 keys x 128 cols, stride 272), b64 writes ----
    // lane holds 4 CONSECUTIVE cols (rcols lg*4+e) for key nk*16+l15.
#pragma unroll
    for (int mr = 0; mr < 4; ++mr) {
#pragma unroll
        for (int nk = 0; nk < 4; ++nk) {
            char* Ts = T + ((wq * 2 + (nk >> 1)) * 2 + (wc >> 1)) * 8704;
            int trow = (nk & 1) * 16 + l15;
            int tcol = (wc & 1) * 64 + mr * 16 + lg * 4;
            union { bf16x4 v; u16 u[4]; } p;
            p.u[0] = f2bf(acc[mr][nk][0]); p.u[1] = f2bf(acc[mr][nk][1]);
            p.u[2] = f2bf(acc[mr][nk][2]); p.u[3] = f2bf(acc[mr][nk][3]);
            *(bf16x4*)(Ts + trow * 272 + tcol * 2) = p.v;
        }
    }
    block_sync_lds();   // T + normP visible

    // ==== sims phase: wave = (qh = w>>2: 128 queries, kq = w&3: 32 keys) ====
    const int qh = w >> 2;
    const int kq = w & 3;
    const int fmask8 = (cg < 2) ? 0x80 : (cg == 2) ? 0x88 : 0xA8;

    f32x4 acc2[8][2];
#pragma unroll
    for (int mf = 0; mf < 8; ++mf) { acc2[mf][0] = (f32x4){0,0,0,0}; acc2[mf][1] = (f32x4){0,0,0,0}; }

    int u    = (cg < 2) ? cg : (cg == 2) ? 2 : 4;
    int prev = 0;

#pragma unroll
    for (int st = 0; st < 8; ++st) {
        // A-frags (Qpack, L2-hot): fid = (cg*8+st)*16 + qh*8 + mf
        bf16x8 aq[8];
#pragma unroll
        for (int mf = 0; mf < 8; ++mf)
            aq[mf] = *(const bf16x8*)((const char*)Qp +
                        (long long)((cg * 8 + st) * 16 + qh * 8 + mf) * 1024 + lam * 16);
        // B-frags from T: key = kq*32 + nf*16 + l15, cols st*32 + lg*8 + j
        bf16x8 bk[2];
        {
            const char* Ts = T + (kq * 2 + (st >> 2)) * 8704;
#pragma unroll
            for (int nf = 0; nf < 2; ++nf)
                bk[nf] = *(const bf16x8*)(Ts + (nf * 16 + l15) * 272 + (st & 3) * 64 + lg * 16);
        }
#pragma unroll
        for (int mf = 0; mf < 8; ++mf) {
            acc2[mf][0] = __builtin_amdgcn_mfma_f32_16x16x32_bf16(aq[mf], bk[0], acc2[mf][0], 0, 0, 0);
            acc2[mf][1] = __builtin_amdgcn_mfma_f32_16x16x32_bf16(aq[mf], bk[1], acc2[mf][1], 0, 0, 0);
        }

        if ((fmask8 >> st) & 1) {
            // ---- flush unit u: cols [prev..st]*32, wc quarters prev>>1 .. st>>1 ----
            const int wc0 = prev >> 1, wc1 = st >> 1;
            float rn[2];
#pragma unroll
            for (int nf = 0; nf < 2; ++nf) {
                int key = kq * 32 + nf * 16 + l15;
                float nv = 0.f;
                for (int q2 = wc0; q2 <= wc1; ++q2) nv += normP[q2 * 128 + key];
                rn[nf] = 1.0f / fmaxf(sqrtf(nv), 1e-3f);
            }
#pragma unroll
            for (int mf = 0; mf < 8; ++mf) {
#pragma unroll
                for (int e = 0; e < 4; ++e) {
                    float v0 = acc2[mf][0][e] * rn[0];
                    float v1 = acc2[mf][1][e] * rn[1];
                    float bv; int bi5;
                    if (v1 > v0) { bv = v1; bi5 = 16 + l15; }
                    else         { bv = v0; bi5 = l15; }
                    unsigned int ui = __float_as_uint(bv);
                    unsigned int mp = ui ^ (((int)ui < 0) ? 0xFFFFFFFFu : 0x80000000u);
                    unsigned int enc = (mp & 0xFFFFFFC0u) | (63u - (unsigned int)bi5);
#pragma unroll
                    for (int mask = 1; mask <= 8; mask <<= 1) {
                        unsigned int o = __shfl_xor(enc, mask);
                        enc = (o > enc) ? o : enc;
                    }
                    if (l15 == 0) {
                        unsigned int gl = (unsigned int)(kb + kq * 32 + (63 - (int)(enc & 63u)));
                        unsigned long long e64 =
                            ((unsigned long long)(enc & 0xFFFFFFC0u) << 32) |
                            (unsigned long long)(0xFFFFFFFFu - gl);
                        int qq = qh * 128 + mf * 16 + lg * 4 + e;
                        unsigned long long* addr = best + u * BZn + qq;
                        if (e64 > *addr) atomicMax(addr, e64);
                    }
                    acc2[mf][0][e] = 0.f;
                    acc2[mf][1][e] = 0.f;
                }
            }
            ++u;
            prev = st + 1;
        }
    }
}

// ---------------- finish: exact f32 cosine of the winners ----------------
__global__ void k_final(const float* __restrict__ keys, const float* __restrict__ R,
                        const float* __restrict__ Qrot,
                        const unsigned long long* __restrict__ best, float* __restrict__ out) {
    const int fid = blockIdx.x;
    const int u = fid >> 8, b = fid & 255;
    int off, d;
    if (u < 2)      { off = u * 256;            d = 256; }
    else if (u < 5) { off = 512 + (u - 2) * 128; d = 128; }
    else            { off = 896 + (u - 5) * 64;  d = 64;  }

    unsigned long long ent = best[fid];
    if (ent == 0ull) return;

    __shared__ float krow[Hd];
    __shared__ float red[12];
    const int t = threadIdx.x;
    unsigned int gl = 0xFFFFFFFFu - (unsigned int)(ent & 0xFFFFFFFFull);
    const float* kp = keys + (long long)gl * Hd;
    *(float4*)(&krow[t * 4]) = *(const float4*)(kp + t * 4);
    __syncthreads();

    float pn = 0.f, pq = 0.f, pk = 0.f;
    if (t < d) {
        float kr = 0.f;
        for (int k = 0; k < Hd; ++k) kr += krow[k] * R[(long long)k * Hd + off + t];
        float qv = Qrot[(long long)b * Hd + off + t];
        pn = qv * kr; pq = qv * qv; pk = kr * kr;
    }
    for (int mask = 1; mask <= 32; mask <<= 1) {
        pn += __shfl_xor(pn, mask); pq += __shfl_xor(pq, mask); pk += __shfl_xor(pk, mask);
    }
    if ((t & 63) == 0) { red[t >> 6] = pn; red[4 + (t >> 6)] = pq; red[8 + (t >> 6)] = pk; }
    __syncthreads();
    if (t == 0) {
        float nm = red[0] + red[1] + red[2] + red[3];
        float qq = red[4] + red[5] + red[6] + red[7];
        float kk = red[8] + red[9] + red[10] + red[11];
        float cosv = nm / (fmaxf(sqrtf(qq), 1e-8f) * fmaxf(sqrtf(kk), 1e-8f));
        atomicAdd(out, -cosv * (float)d / (256.0f * 1024.0f));
    }
}

// ---------------- launch ----------------
extern "C" void kernel_launch(void* const* d_in, const int* in_sizes, int n_in,
                              void* d_out, int out_size, void* d_ws, size_t ws_size,
                              hipStream_t stream) {
    (void)in_sizes; (void)n_in; (void)out_size; (void)ws_size;
    const float* query = (const float*)d_in[0];
    const float* keys  = (const float*)d_in[1];
    const float* R     = (const float*)d_in[2];
    float* out = (float*)d_out;
    char* ws = (char*)d_ws;

    unsigned long long* best = (unsigned long long*)ws;           // 16 KiB slot
    float* Qrot   = (float*)(ws + 16384);                         // 1 MiB
    u16*   Rpack  = (u16*)(ws + 16384 + 1048576);                 // 2 MiB
    u16*   Qpack  = (u16*)(ws + 16384 + 1048576 + 2097152);       // 512 KiB

    hipMemsetAsync(best, 0, NU * BZn * sizeof(unsigned long long), stream);
    hipMemsetAsync(out, 0, sizeof(float), stream);

    k_qrot <<<64,  256, 0, stream>>>(query, R, Qrot);
    k_rpack<<<512, 256, 0, stream>>>(R, Rpack);
    k_qpack<<<128, 256, 0, stream>>>(Qrot, Qpack);

    hipFuncSetAttribute((const void*)k_fused,
                        hipFuncAttributeMaxDynamicSharedMemorySize, LDS_TOT);
    k_fused<<<(MTOT / 128) * 4, 512, LDS_TOT, stream>>>(keys, Rpack, Qpack, best);

    k_final<<<NU * BZn, 256, 0, stream>>>(keys, R, Qrot, best, out);
}